// Round 9
// baseline (254.591 us; speedup 1.0000x reference)
//
#include <hip/hip_runtime.h>
#include <hip/hip_bf16.h>
#include <hip/hip_cooperative_groups.h>
#include <math.h>

namespace cg = cooperative_groups;

// Problem constants (B=16, T=2048, D=64, K=8192)
#define N_ROWS 32768
#define KCODES 8192
#define DDIM 64

typedef __attribute__((ext_vector_type(8))) short bf16x8;
typedef __attribute__((ext_vector_type(4))) float f32x4;

// ===================== FAST PATH =====================
// ws layout (bytes):
//   O_XBF   = 0        : x_bf (fallback path only)
//   O_QPERM = 4 MB     : codebook in MFMA-B-frag order (1 MB)
//   O_X2    = 5242880  : x2  N f32 (fallback path only)
//   O_E2    = 5373952  : e2  K f32
//   O_E2MAX = 5406720  : 1 f32 (atomicMax int-bits)
#define O_XBF   0
#define O_QPERM 4194304UL
#define O_X2    5242880UL
#define O_E2    5373952UL
#define O_E2MAX 5406720UL
#define O_SLOTS 5668880UL
#define WS_NEEDED (O_SLOTS + (size_t)N_ROWS * 16 * 4)
#define CAPL 32  // LDS candidate capacity per row (observed ~1-2; overflow has exact fallback)

__device__ __forceinline__ unsigned short f2bf(float f) {
    __hip_bfloat16 h = __float2bfloat16(f);  // RNE
    union { __hip_bfloat16 b; unsigned short u; } u;
    u.b = h;
    return u.u;
}

__device__ __forceinline__ float bf2f(unsigned short u) {
    return __uint_as_float(((unsigned int)u) << 16);  // exact bf16 -> f32
}

// ---- single cooperative kernel: prep + screen + finalize ----
// Grid 512 x 512 thr (2 blocks/CU, co-resident).
// Phase 0: block converts its 64 x-rows -> xs_lds (bf16) + x2_lds (exact v1
//   numpy-pairwise order: per-lane v*v with contract off, sequential m=0..7 adds via
//   8-lane shfl broadcast, v1's exact pairwise tree). Its 16 cb rows -> qperm + e2
//   (global, same exact order) + e2max (device atomicMax; max is order-independent).
// grid.sync() makes qperm/e2/e2max visible to all blocks.
// Phase A: round-6-verified 2-deep-prefetch MFMA sweep on s = dot - e2/2 (e2 folded
//   into MFMA C-init), per-row per-128-code-group maxima -> LDS (lossless pre-filter).
// Threshold: per-row gmax from tilemax, thr = gmax - margin (validated s-space margin).
// Phase B (row-exact): worklist of (row,group) pairs with tilemax >= thr[row]; fp32
//   fmaf re-score of the SAME bf16 inputs; candidates -> LDS lists.
// Phase C (== old finalize2 arithmetic, validated absmax 0): exact fp32 re-score,
//   8 lanes/row, lexicographic (dist,code) min; writes x_q_st and index.
__global__ __launch_bounds__(512) void vq_fused_kernel(
    const float* __restrict__ xg, const float* __restrict__ cbg,
    uint4* __restrict__ qperm, float* __restrict__ e2g,
    int* __restrict__ e2max_bits, float* __restrict__ out) {
#pragma clang fp contract(off)
    __shared__ float tilemax_lds[64 * 64];       // [group g=0..63][row r=0..63], 16 KB
    __shared__ unsigned short xs_lds[64][64];    // bf16 x rows, 8 KB
    __shared__ unsigned int wl[4096];            // worklist (g<<6)|r, 16 KB
    __shared__ float thr_lds[64];                // per-row threshold in s-space
    __shared__ float x2_lds[64];                 // per-row x2 (exact v1 value)
    __shared__ int cnt_lds[64];                  // per-row candidate counts
    __shared__ int slots_lds[64][CAPL];          // per-row candidate codes, 8 KB
    __shared__ int wcnt;

    const int tid = threadIdx.x;
    const int w = tid >> 6;      // wave 0..7
    const int lane = tid & 63;
    const int l15 = lane & 15;
    const int quad = lane >> 4;
    const int row0 = blockIdx.x * 64;
    const int T0 = w * 64;       // this wave's first 16-code tile (of 512 total)

    if (tid == 0) wcnt = 0;
    if (tid < 64) cnt_lds[tid] = 0;

    // ---------------- Phase 0a: own 64 x-rows -> xs_lds + x2_lds ----------------
    {
        const int r0 = tid >> 3;  // row 0..63
        const int h0 = tid & 7;   // 8-float chunk 0..7
        const float* src = xg + (size_t)(row0 + r0) * DDIM + h0 * 8;
        float4 v0 = ((const float4*)src)[0];
        float4 v1 = ((const float4*)src)[1];
        ushort4 a, b;
        a.x = f2bf(v0.x); a.y = f2bf(v0.y); a.z = f2bf(v0.z); a.w = f2bf(v0.w);
        b.x = f2bf(v1.x); b.y = f2bf(v1.y); b.z = f2bf(v1.z); b.w = f2bf(v1.w);
        union { struct { ushort4 lo, hi; } s; uint4 u; } pk;
        pk.s.lo = a; pk.s.hi = b;
        *(uint4*)&xs_lds[r0][h0 * 8] = pk.u;

        // exact v1 sumsq: sq per lane (contract off), sequential m=0..7 adds per j,
        // then v1's pairwise tree. Lane base+m holds chunk m of the row.
        float sq[8] = {v0.x * v0.x, v0.y * v0.y, v0.z * v0.z, v0.w * v0.w,
                       v1.x * v1.x, v1.y * v1.y, v1.z * v1.z, v1.w * v1.w};
        const int base = lane & ~7;
        float acc[8];
#pragma unroll
        for (int j = 0; j < 8; ++j) acc[j] = __shfl(sq[j], base, 64);
#pragma unroll
        for (int m = 1; m < 8; ++m)
#pragma unroll
            for (int j = 0; j < 8; ++j) acc[j] = acc[j] + __shfl(sq[j], base + m, 64);
        float s = ((acc[0] + acc[1]) + (acc[2] + acc[3])) +
                  ((acc[4] + acc[5]) + (acc[6] + acc[7]));
        if (h0 == 0) x2_lds[r0] = s;
    }

    // ---------------- Phase 0b: own 16 cb rows -> qperm + e2 + e2max ----------------
    if (tid < 128) {
        const int c = tid >> 3;   // code within block's 16
        const int h = tid & 7;    // chunk
        const int code = blockIdx.x * 16 + c;
        const float* src = cbg + (size_t)code * DDIM + h * 8;
        float4 v0 = ((const float4*)src)[0];
        float4 v1 = ((const float4*)src)[1];
        ushort4 a, b;
        a.x = f2bf(v0.x); a.y = f2bf(v0.y); a.z = f2bf(v0.z); a.w = f2bf(v0.w);
        b.x = f2bf(v1.x); b.y = f2bf(v1.y); b.z = f2bf(v1.z); b.w = f2bf(v1.w);
        union { struct { ushort4 lo, hi; } s; uint4 u; } pk;
        pk.s.lo = a; pk.s.hi = b;
        // frag-order: slot = ((code>>4)*2 + (h>>2))*64 + (h&3)*16 + (code&15); code>>4==bid
        const int slot = (blockIdx.x * 2 + (h >> 2)) * 64 + (h & 3) * 16 + c;
        qperm[slot] = pk.u;

        float sq[8] = {v0.x * v0.x, v0.y * v0.y, v0.z * v0.z, v0.w * v0.w,
                       v1.x * v1.x, v1.y * v1.y, v1.z * v1.z, v1.w * v1.w};
        const int base = lane & ~7;
        float acc[8];
#pragma unroll
        for (int j = 0; j < 8; ++j) acc[j] = __shfl(sq[j], base, 64);
#pragma unroll
        for (int m = 1; m < 8; ++m)
#pragma unroll
            for (int j = 0; j < 8; ++j) acc[j] = acc[j] + __shfl(sq[j], base + m, 64);
        float s = ((acc[0] + acc[1]) + (acc[2] + acc[3])) +
                  ((acc[4] + acc[5]) + (acc[6] + acc[7]));
        if (h == 0) e2g[code] = s;
        // wave max (all lanes hold their group's s redundantly), one atomic per wave
        float wm = s;
#pragma unroll
        for (int m = 1; m < 64; m <<= 1) wm = fmaxf(wm, __shfl_xor(wm, m, 64));
        if (lane == 0) atomicMax(e2max_bits, __float_as_int(wm));
    }

    __threadfence();
    cg::this_grid().sync();

    // A-fragments from LDS (same layout as prior global xbf reads)
    bf16x8 afrag[4][2];
#pragma unroll
    for (int rt = 0; rt < 4; ++rt)
#pragma unroll
        for (int s = 0; s < 2; ++s)
            afrag[rt][s] = *(const bf16x8*)&xs_lds[rt * 16 + l15][s * 32 + quad * 8];

    const uint4* pB = qperm + (size_t)T0 * 128 + lane;
    const float* pE = e2g + T0 * 16 + l15;

    // ---------------- Phase A: full sweep with tilemax tracking ----------------
    bf16x8 b0[2], b1[2];
    float ee2[2];
#pragma unroll
    for (int i = 0; i < 2; ++i) {
        b0[i] = *(const bf16x8*)(pB + (size_t)i * 128);
        b1[i] = *(const bf16x8*)(pB + (size_t)i * 128 + 64);
        ee2[i] = pE[i * 16];
    }

    float tmax[4][4];
#pragma unroll
    for (int rt = 0; rt < 4; ++rt)
#pragma unroll
        for (int reg = 0; reg < 4; ++reg) tmax[rt][reg] = -3.0e38f;

    for (int g = 0; g < 8; ++g) {
#pragma unroll 2
        for (int j = 0; j < 8; ++j) {
            const int t = g * 8 + j;
            const int buf = t & 1;
            const bf16x8 B0 = b0[buf];
            const bf16x8 B1 = b1[buf];
            const float eh = -0.5f * ee2[buf];
            if (t < 62) {
                const uint4* p = pB + (size_t)(t + 2) * 128;
                b0[buf] = *(const bf16x8*)p;
                b1[buf] = *(const bf16x8*)(p + 64);
                ee2[buf] = pE[(t + 2) * 16];
            }
            const f32x4 cin = {eh, eh, eh, eh};
#pragma unroll
            for (int rt = 0; rt < 4; ++rt) {
                f32x4 acc = __builtin_amdgcn_mfma_f32_16x16x32_bf16(afrag[rt][0], B0, cin, 0, 0, 0);
                acc = __builtin_amdgcn_mfma_f32_16x16x32_bf16(afrag[rt][1], B1, acc, 0, 0, 0);
#pragma unroll
                for (int reg = 0; reg < 4; ++reg)
                    tmax[rt][reg] = fmaxf(tmax[rt][reg], acc[reg]);
            }
        }
        // group-end: reduce over the 16 code-columns (l15 lanes), commit per-row tile max
        const int gidx = w * 8 + g;
#pragma unroll
        for (int rt = 0; rt < 4; ++rt)
#pragma unroll
            for (int reg = 0; reg < 4; ++reg) {
                float v = tmax[rt][reg];
                v = fmaxf(v, __shfl_xor(v, 1, 64));
                v = fmaxf(v, __shfl_xor(v, 2, 64));
                v = fmaxf(v, __shfl_xor(v, 4, 64));
                v = fmaxf(v, __shfl_xor(v, 8, 64));
                if (l15 == 0) tilemax_lds[gidx * 64 + rt * 16 + quad * 4 + reg] = v;
                tmax[rt][reg] = -3.0e38f;
            }
    }
    __syncthreads();

    // ---------------- block-local gmax -> threshold ----------------
    if (tid < 64) {
        float gs = -3.0e38f;
        for (int e = 0; e < 64; ++e) gs = fmaxf(gs, tilemax_lds[e * 64 + tid]);
        const float e2max = __int_as_float(*e2max_bits);
        // s-space margin == half the validated dist-space margin (dist = x2 - 2s)
        thr_lds[tid] = gs - 0.005f * sqrtf(x2_lds[tid] * e2max) - 0.01f;
    }
    __syncthreads();

    // ---------------- worklist build: row-exact (row, group) pairs ----------------
    for (int idx = tid; idx < 4096; idx += 512) {
        if (tilemax_lds[idx] >= thr_lds[idx & 63]) {
            int pos = atomicAdd(&wcnt, 1);
            wl[pos] = (unsigned int)idx;  // layout [g][r]: idx = (g<<6)|r
        }
    }
    __syncthreads();

    // ---------------- Phase B: VALU re-score of flagged pairs only ----------------
    const int nwl = wcnt;
    for (int p = w; p < nwl; p += 8) {
        const unsigned int e = wl[p];
        const int r = (int)(e & 63u);
        const int g = (int)(e >> 6);
        const float thr_r = thr_lds[r];
#pragma unroll
        for (int hh = 0; hh < 2; ++hh) {
            const int c = g * 128 + hh * 64 + lane;
            float s = -0.5f * e2g[c];
            const int cg = c >> 4, cl = c & 15;
#pragma unroll
            for (int h = 0; h < 8; ++h) {
                const int slot = (cg * 2 + (h >> 2)) * 64 + (h & 3) * 16 + cl;
                union { uint4 u; unsigned short us[8]; } qd, xd;
                qd.u = qperm[slot];
                xd.u = *(const uint4*)&xs_lds[r][h * 8];
#pragma unroll
                for (int k = 0; k < 8; ++k)
                    s = fmaf(bf2f(xd.us[k]), bf2f(qd.us[k]), s);
            }
            if (s >= thr_r) {  // ~1-2 codes/row over all K
                int pos = atomicAdd(&cnt_lds[r], 1);
                if (pos < CAPL) slots_lds[r][pos] = c;
            }
        }
    }
    __syncthreads();

    // ---------------- Phase C: exact fp32 re-score + output (== old finalize2) -------
    const int sub = lane >> 3;   // row within wave's 8-row group
    const int ln8 = lane & 7;    // 8 lanes per row
    const int r = w * 8 + sub;
    const int row = row0 + r;
    const int c = cnt_lds[r];
    const float x2v = x2_lds[r];
    const float4* xv4 = (const float4*)(xg + (size_t)row * DDIM);

    float bv = 3.0e38f;
    int bi = 0x7fffffff;
    if (c <= CAPL) {
        for (int i = ln8; i < c; i += 8) {
            int code = slots_lds[r][i];
            float xe = 0.0f;
            const float4* e4 = (const float4*)(cbg + (size_t)code * DDIM);
#pragma unroll
            for (int q = 0; q < 16; ++q) {
                float4 xv = xv4[q];
                float4 ev = e4[q];
                xe = fmaf(xv.x, ev.x, xe);
                xe = fmaf(xv.y, ev.y, xe);
                xe = fmaf(xv.z, ev.z, xe);
                xe = fmaf(xv.w, ev.w, xe);
            }
            float ts = x2v + e2g[code];
            float dist = fmaf(-2.0f, xe, ts);
            if (dist < bv || (dist == bv && code < bi)) { bv = dist; bi = code; }
        }
    } else {
        // backstop: full scan (overflow; should never trigger)
        for (int code = ln8; code < KCODES; code += 8) {
            float xe = 0.0f;
            const float4* e4 = (const float4*)(cbg + (size_t)code * DDIM);
#pragma unroll
            for (int q = 0; q < 16; ++q) {
                float4 xv = xv4[q];
                float4 ev = e4[q];
                xe = fmaf(xv.x, ev.x, xe);
                xe = fmaf(xv.y, ev.y, xe);
                xe = fmaf(xv.z, ev.z, xe);
                xe = fmaf(xv.w, ev.w, xe);
            }
            float ts = x2v + e2g[code];
            float dist = fmaf(-2.0f, xe, ts);
            if (dist < bv || (dist == bv && code < bi)) { bv = dist; bi = code; }
        }
    }
    // 8-lane lexicographic (dist, code) min reduce (associative + commutative)
#pragma unroll
    for (int m = 1; m < 8; m <<= 1) {
        float ov = __shfl_xor(bv, m, 64);
        int oi = __shfl_xor(bi, m, 64);
        if (ov < bv || (ov == bv && oi < bi)) { bv = ov; bi = oi; }
    }
    // outputs: x_q_st = x + (q - x), elementwise f32 (identical to old finalize2)
    {
        const float4* qs4 = (const float4*)(cbg + (size_t)bi * DDIM);
        float4* os4 = (float4*)(out + (size_t)row * DDIM);
#pragma unroll
        for (int i = 0; i < 2; ++i) {
            float4 xv = xv4[ln8 * 2 + i];
            float4 qv = qs4[ln8 * 2 + i];
            float4 ov;
            ov.x = xv.x + (qv.x - xv.x);
            ov.y = xv.y + (qv.y - xv.y);
            ov.z = xv.z + (qv.z - xv.z);
            ov.w = xv.w + (qv.w - xv.w);
            os4[ln8 * 2 + i] = ov;
        }
        if (ln8 == 0) out[(size_t)N_ROWS * DDIM + row] = (float)bi;
    }
}

// ===================== VERIFIED 2-KERNEL PATH (round-8, 140 us) =====================
// Kept as fallback if cooperative launch is unavailable.
__global__ __launch_bounds__(256) void prep_kernel(const float* __restrict__ x,
                                                   const float* __restrict__ cb,
                                                   unsigned short* __restrict__ xbf,
                                                   uint4* __restrict__ qperm,
                                                   float* __restrict__ x2,
                                                   float* __restrict__ e2,
                                                   int* __restrict__ e2max_bits) {
#pragma clang fp contract(off)
    __shared__ float xrow[64][68];

    const int tid = threadIdx.x;
    const int rloc = tid >> 2;
    const int q4 = tid & 3;
    const int grow = blockIdx.x * 64 + rloc;
    const bool iscb = (grow >= N_ROWS);
    const int r = iscb ? (grow - N_ROWS) : grow;
    const float* src = iscb ? (cb + (size_t)r * DDIM) : (x + (size_t)r * DDIM);

    float4 v[4];
#pragma unroll
    for (int h2 = 0; h2 < 4; ++h2) v[h2] = ((const float4*)src)[q4 * 4 + h2];
#pragma unroll
    for (int h2 = 0; h2 < 4; ++h2)
        *(float4*)&xrow[rloc][q4 * 16 + h2 * 4] = v[h2];

    uint4 ch[2];
#pragma unroll
    for (int hh = 0; hh < 2; ++hh) {
        float4 v0 = v[hh * 2];
        float4 v1 = v[hh * 2 + 1];
        ushort4 a, b;
        a.x = f2bf(v0.x); a.y = f2bf(v0.y); a.z = f2bf(v0.z); a.w = f2bf(v0.w);
        b.x = f2bf(v1.x); b.y = f2bf(v1.y); b.z = f2bf(v1.z); b.w = f2bf(v1.w);
        union { struct { ushort4 lo, hi; } s; uint4 u; } pk;
        pk.s.lo = a; pk.s.hi = b;
        ch[hh] = pk.u;
    }
    if (!iscb) {
        uint4* dst = (uint4*)(xbf + (size_t)r * DDIM);
        dst[q4 * 2 + 0] = ch[0];
        dst[q4 * 2 + 1] = ch[1];
    } else {
        const int g = r >> 4, l15 = r & 15;
#pragma unroll
        for (int hh = 0; hh < 2; ++hh) {
            const int h = q4 * 2 + hh;
            const int slot = (g * 2 + (h >> 2)) * 64 + (h & 3) * 16 + l15;
            qperm[slot] = ch[hh];
        }
    }
    __syncthreads();

    if (tid < 64) {
        float acc[8];
#pragma unroll
        for (int j = 0; j < 8; ++j) { float vv = xrow[tid][j]; acc[j] = vv * vv; }
#pragma unroll
        for (int i = 8; i < 64; i += 8)
#pragma unroll
            for (int j = 0; j < 8; ++j) { float vv = xrow[tid][i + j]; acc[j] = acc[j] + vv * vv; }
        float s = ((acc[0] + acc[1]) + (acc[2] + acc[3])) + ((acc[4] + acc[5]) + (acc[6] + acc[7]));
        const int grow2 = blockIdx.x * 64 + tid;
        if (grow2 < N_ROWS) {
            x2[grow2] = s;
        } else {
            e2[grow2 - N_ROWS] = s;
            float wm = s;
#pragma unroll
            for (int m = 1; m < 64; m <<= 1) wm = fmaxf(wm, __shfl_xor(wm, m, 64));
            if (tid == 0) atomicMax(e2max_bits, __float_as_int(wm));
        }
    }
}

__global__ __launch_bounds__(512) void screen_fused_kernel(
    const unsigned short* __restrict__ xbf, const uint4* __restrict__ qperm,
    const float* __restrict__ xg, const float* __restrict__ cbg,
    const float* __restrict__ x2g, const float* __restrict__ e2g,
    const int* __restrict__ e2max_bits, float* __restrict__ out) {
    __shared__ float tilemax_lds[64 * 64];
    __shared__ unsigned short xs_lds[64][64];
    __shared__ unsigned int wl[4096];
    __shared__ float thr_lds[64];
    __shared__ int cnt_lds[64];
    __shared__ int slots_lds[64][CAPL];
    __shared__ int wcnt;

    const int tid = threadIdx.x;
    const int w = tid >> 6;
    const int lane = tid & 63;
    const int l15 = lane & 15;
    const int quad = lane >> 4;
    const int row0 = blockIdx.x * 64;
    const int T0 = w * 64;

    ((uint4*)xs_lds)[tid] = *((const uint4*)(xbf + (size_t)row0 * DDIM) + tid);
    if (tid == 0) wcnt = 0;
    if (tid < 64) cnt_lds[tid] = 0;

    bf16x8 afrag[4][2];
#pragma unroll
    for (int rt = 0; rt < 4; ++rt)
#pragma unroll
        for (int s = 0; s < 2; ++s)
            afrag[rt][s] = *(const bf16x8*)(xbf + (size_t)(row0 + rt * 16 + l15) * DDIM +
                                            s * 32 + quad * 8);

    const uint4* pB = qperm + (size_t)T0 * 128 + lane;
    const float* pE = e2g + T0 * 16 + l15;

    bf16x8 b0[2], b1[2];
    float ee2[2];
#pragma unroll
    for (int i = 0; i < 2; ++i) {
        b0[i] = *(const bf16x8*)(pB + (size_t)i * 128);
        b1[i] = *(const bf16x8*)(pB + (size_t)i * 128 + 64);
        ee2[i] = pE[i * 16];
    }

    float tmax[4][4];
#pragma unroll
    for (int rt = 0; rt < 4; ++rt)
#pragma unroll
        for (int reg = 0; reg < 4; ++reg) tmax[rt][reg] = -3.0e38f;

    for (int g = 0; g < 8; ++g) {
#pragma unroll 2
        for (int j = 0; j < 8; ++j) {
            const int t = g * 8 + j;
            const int buf = t & 1;
            const bf16x8 B0 = b0[buf];
            const bf16x8 B1 = b1[buf];
            const float eh = -0.5f * ee2[buf];
            if (t < 62) {
                const uint4* p = pB + (size_t)(t + 2) * 128;
                b0[buf] = *(const bf16x8*)p;
                b1[buf] = *(const bf16x8*)(p + 64);
                ee2[buf] = pE[(t + 2) * 16];
            }
            const f32x4 cin = {eh, eh, eh, eh};
#pragma unroll
            for (int rt = 0; rt < 4; ++rt) {
                f32x4 acc = __builtin_amdgcn_mfma_f32_16x16x32_bf16(afrag[rt][0], B0, cin, 0, 0, 0);
                acc = __builtin_amdgcn_mfma_f32_16x16x32_bf16(afrag[rt][1], B1, acc, 0, 0, 0);
#pragma unroll
                for (int reg = 0; reg < 4; ++reg)
                    tmax[rt][reg] = fmaxf(tmax[rt][reg], acc[reg]);
            }
        }
        const int gidx = w * 8 + g;
#pragma unroll
        for (int rt = 0; rt < 4; ++rt)
#pragma unroll
            for (int reg = 0; reg < 4; ++reg) {
                float v = tmax[rt][reg];
                v = fmaxf(v, __shfl_xor(v, 1, 64));
                v = fmaxf(v, __shfl_xor(v, 2, 64));
                v = fmaxf(v, __shfl_xor(v, 4, 64));
                v = fmaxf(v, __shfl_xor(v, 8, 64));
                if (l15 == 0) tilemax_lds[gidx * 64 + rt * 16 + quad * 4 + reg] = v;
                tmax[rt][reg] = -3.0e38f;
            }
    }
    __syncthreads();

    if (tid < 64) {
        float gs = -3.0e38f;
        for (int e = 0; e < 64; ++e) gs = fmaxf(gs, tilemax_lds[e * 64 + tid]);
        const float e2max = __int_as_float(*e2max_bits);
        thr_lds[tid] = gs - 0.005f * sqrtf(x2g[row0 + tid] * e2max) - 0.01f;
    }
    __syncthreads();

    for (int idx = tid; idx < 4096; idx += 512) {
        if (tilemax_lds[idx] >= thr_lds[idx & 63]) {
            int pos = atomicAdd(&wcnt, 1);
            wl[pos] = (unsigned int)idx;
        }
    }
    __syncthreads();

    const int nwl = wcnt;
    for (int p = w; p < nwl; p += 8) {
        const unsigned int e = wl[p];
        const int r = (int)(e & 63u);
        const int g = (int)(e >> 6);
        const float thr_r = thr_lds[r];
#pragma unroll
        for (int hh = 0; hh < 2; ++hh) {
            const int c = g * 128 + hh * 64 + lane;
            float s = -0.5f * e2g[c];
            const int cg = c >> 4, cl = c & 15;
#pragma unroll
            for (int h = 0; h < 8; ++h) {
                const int slot = (cg * 2 + (h >> 2)) * 64 + (h & 3) * 16 + cl;
                union { uint4 u; unsigned short us[8]; } qd, xd;
                qd.u = qperm[slot];
                xd.u = *(const uint4*)&xs_lds[r][h * 8];
#pragma unroll
                for (int k = 0; k < 8; ++k)
                    s = fmaf(bf2f(xd.us[k]), bf2f(qd.us[k]), s);
            }
            if (s >= thr_r) {
                int pos = atomicAdd(&cnt_lds[r], 1);
                if (pos < CAPL) slots_lds[r][pos] = c;
            }
        }
    }
    __syncthreads();

    const int sub = lane >> 3;
    const int ln8 = lane & 7;
    const int r = w * 8 + sub;
    const int row = row0 + r;
    const int c = cnt_lds[r];
    const float x2v = x2g[row];
    const float4* xv4 = (const float4*)(xg + (size_t)row * DDIM);

    float bv = 3.0e38f;
    int bi = 0x7fffffff;
    if (c <= CAPL) {
        for (int i = ln8; i < c; i += 8) {
            int code = slots_lds[r][i];
            float xe = 0.0f;
            const float4* e4 = (const float4*)(cbg + (size_t)code * DDIM);
#pragma unroll
            for (int q = 0; q < 16; ++q) {
                float4 xv = xv4[q];
                float4 ev = e4[q];
                xe = fmaf(xv.x, ev.x, xe);
                xe = fmaf(xv.y, ev.y, xe);
                xe = fmaf(xv.z, ev.z, xe);
                xe = fmaf(xv.w, ev.w, xe);
            }
            float ts = x2v + e2g[code];
            float dist = fmaf(-2.0f, xe, ts);
            if (dist < bv || (dist == bv && code < bi)) { bv = dist; bi = code; }
        }
    } else {
        for (int code = ln8; code < KCODES; code += 8) {
            float xe = 0.0f;
            const float4* e4 = (const float4*)(cbg + (size_t)code * DDIM);
#pragma unroll
            for (int q = 0; q < 16; ++q) {
                float4 xv = xv4[q];
                float4 ev = e4[q];
                xe = fmaf(xv.x, ev.x, xe);
                xe = fmaf(xv.y, ev.y, xe);
                xe = fmaf(xv.z, ev.z, xe);
                xe = fmaf(xv.w, ev.w, xe);
            }
            float ts = x2v + e2g[code];
            float dist = fmaf(-2.0f, xe, ts);
            if (dist < bv || (dist == bv && code < bi)) { bv = dist; bi = code; }
        }
    }
#pragma unroll
    for (int m = 1; m < 8; m <<= 1) {
        float ov = __shfl_xor(bv, m, 64);
        int oi = __shfl_xor(bi, m, 64);
        if (ov < bv || (ov == bv && oi < bi)) { bv = ov; bi = oi; }
    }
    {
        const float4* qs4 = (const float4*)(cbg + (size_t)bi * DDIM);
        float4* os4 = (float4*)(out + (size_t)row * DDIM);
#pragma unroll
        for (int i = 0; i < 2; ++i) {
            float4 xv = xv4[ln8 * 2 + i];
            float4 qv = qs4[ln8 * 2 + i];
            float4 ov;
            ov.x = xv.x + (qv.x - xv.x);
            ov.y = xv.y + (qv.y - xv.y);
            ov.z = xv.z + (qv.z - xv.z);
            ov.w = xv.w + (qv.w - xv.w);
            os4[ln8 * 2 + i] = ov;
        }
        if (ln8 == 0) out[(size_t)N_ROWS * DDIM + row] = (float)bi;
    }
}

// ===================== FALLBACK PATH (round-1, correct at 493 us) =====================
#define SPLITK 4
#define KPER (KCODES / SPLITK)
#define TM 128
#define TKT 128
#define NTILES (KPER / TKT)
#define LDSX 132
#define LDSE 132

__global__ __launch_bounds__(256) void sumsq_kernel(const float* __restrict__ x,
                                                    const float* __restrict__ cb,
                                                    float* __restrict__ ws) {
#pragma clang fp contract(off)
    int t = blockIdx.x * 256 + threadIdx.x;
    const float* src;
    float* dst;
    if (t < KCODES) { src = cb + (size_t)t * DDIM; dst = ws + t; }
    else { int r = t - KCODES; src = x + (size_t)r * DDIM; dst = ws + KCODES + r; }
    float acc[8];
#pragma unroll
    for (int j = 0; j < 8; ++j) { float v = src[j]; acc[j] = v * v; }
#pragma unroll
    for (int i = 8; i < 64; i += 8)
#pragma unroll
        for (int j = 0; j < 8; ++j) { float v = src[i + j]; acc[j] = acc[j] + v * v; }
    *dst = ((acc[0] + acc[1]) + (acc[2] + acc[3])) + ((acc[4] + acc[5]) + (acc[6] + acc[7]));
}

__global__ __launch_bounds__(256) void dist_argmin_kernel(const float* __restrict__ x,
                                                          const float* __restrict__ cb,
                                                          const float* __restrict__ e2g,
                                                          const float* __restrict__ x2g,
                                                          float2* __restrict__ partial) {
    __shared__ float smem[DDIM * LDSX + DDIM * LDSE];
    float* Xs = smem;
    float* Es = smem + DDIM * LDSX;
    const int tid = threadIdx.x;
    const int row0 = blockIdx.x * TM;
    const int code0 = blockIdx.y * KPER;
    const int tr = tid >> 4, tc = tid & 15;
    for (int i = tid; i < TM * 16; i += 256) {
        int r = i >> 4, q = i & 15;
        float4 v = ((const float4*)(x + (size_t)(row0 + r) * DDIM))[q];
        Xs[(4 * q + 0) * LDSX + r] = v.x; Xs[(4 * q + 1) * LDSX + r] = v.y;
        Xs[(4 * q + 2) * LDSX + r] = v.z; Xs[(4 * q + 3) * LDSX + r] = v.w;
    }
    float x2v[8];
#pragma unroll
    for (int j = 0; j < 8; ++j) x2v[j] = x2g[row0 + tr * 8 + j];
    float bestV[8]; int bestI[8];
#pragma unroll
    for (int j = 0; j < 8; ++j) { bestV[j] = 3.0e38f; bestI[j] = 0; }
    for (int t = 0; t < NTILES; ++t) {
        __syncthreads();
        const int cbase = code0 + t * TKT;
        for (int i = tid; i < TKT * 16; i += 256) {
            int c = i >> 4, q = i & 15;
            float4 v = ((const float4*)(cb + (size_t)(cbase + c) * DDIM))[q];
            Es[(4 * q + 0) * LDSE + c] = v.x; Es[(4 * q + 1) * LDSE + c] = v.y;
            Es[(4 * q + 2) * LDSE + c] = v.z; Es[(4 * q + 3) * LDSE + c] = v.w;
        }
        __syncthreads();
        float acc[8][8];
#pragma unroll
        for (int a = 0; a < 8; ++a)
#pragma unroll
            for (int b = 0; b < 8; ++b) acc[a][b] = 0.0f;
#pragma unroll 4
        for (int d = 0; d < DDIM; ++d) {
            float xv[8], ev[8];
            float4 xa = *(const float4*)&Xs[d * LDSX + tr * 8];
            float4 xb = *(const float4*)&Xs[d * LDSX + tr * 8 + 4];
            float4 ea = *(const float4*)&Es[d * LDSE + tc * 8];
            float4 eb = *(const float4*)&Es[d * LDSE + tc * 8 + 4];
            xv[0] = xa.x; xv[1] = xa.y; xv[2] = xa.z; xv[3] = xa.w;
            xv[4] = xb.x; xv[5] = xb.y; xv[6] = xb.z; xv[7] = xb.w;
            ev[0] = ea.x; ev[1] = ea.y; ev[2] = ea.z; ev[3] = ea.w;
            ev[4] = eb.x; ev[5] = eb.y; ev[6] = eb.z; ev[7] = eb.w;
#pragma unroll
            for (int a = 0; a < 8; ++a)
#pragma unroll
                for (int b = 0; b < 8; ++b) acc[a][b] = fmaf(xv[a], ev[b], acc[a][b]);
        }
#pragma unroll
        for (int b = 0; b < 8; ++b) {
            int ci = cbase + tc * 8 + b;
            float e2 = e2g[ci];
#pragma unroll
            for (int a = 0; a < 8; ++a) {
                float ts = x2v[a] + e2;
                float dist = fmaf(-2.0f, acc[a][b], ts);
                if (dist < bestV[a]) { bestV[a] = dist; bestI[a] = ci; }
            }
        }
    }
    __syncthreads();
    float* redV = Es;
    int* redI = (int*)(Es + TM * 16);
#pragma unroll
    for (int a = 0; a < 8; ++a) {
        redV[(tr * 8 + a) * 16 + tc] = bestV[a];
        redI[(tr * 8 + a) * 16 + tc] = bestI[a];
    }
    __syncthreads();
    if (tid < TM) {
        float bv = redV[tid * 16];
        int bi = redI[tid * 16];
#pragma unroll
        for (int c = 1; c < 16; ++c) {
            float v = redV[tid * 16 + c];
            int ii = redI[tid * 16 + c];
            if (v < bv || (v == bv && ii < bi)) { bv = v; bi = ii; }
        }
        partial[(size_t)(row0 + tid) * SPLITK + blockIdx.y] = make_float2(bv, __int_as_float(bi));
    }
}

__global__ __launch_bounds__(256) void finalize_kernel(const float2* __restrict__ partial,
                                                       const float* __restrict__ x,
                                                       const float* __restrict__ cb,
                                                       float* __restrict__ out) {
    int t = blockIdx.x * 256 + threadIdx.x;
    int r = t >> 2, j = t & 3;
    float2 p = partial[(size_t)r * SPLITK];
    float bv = p.x;
    int bi = __float_as_int(p.y);
#pragma unroll
    for (int k = 1; k < SPLITK; ++k) {
        float2 q = partial[(size_t)r * SPLITK + k];
        int qi = __float_as_int(q.y);
        if (q.x < bv || (q.x == bv && qi < bi)) { bv = q.x; bi = qi; }
    }
    const float4* xs = (const float4*)(x + (size_t)r * DDIM);
    const float4* qs = (const float4*)(cb + (size_t)bi * DDIM);
    float4* os = (float4*)(out + (size_t)r * DDIM);
#pragma unroll
    for (int i = 0; i < 4; ++i) {
        float4 xv = xs[j * 4 + i];
        float4 qv = qs[j * 4 + i];
        float4 ov;
        ov.x = xv.x + (qv.x - xv.x); ov.y = xv.y + (qv.y - xv.y);
        ov.z = xv.z + (qv.z - xv.z); ov.w = xv.w + (qv.w - xv.w);
        os[j * 4 + i] = ov;
    }
    if (j == 0) out[(size_t)N_ROWS * DDIM + r] = (float)bi;
}

// ===================== LAUNCH =====================
extern "C" void kernel_launch(void* const* d_in, const int* in_sizes, int n_in,
                              void* d_out, int out_size, void* d_ws, size_t ws_size,
                              hipStream_t stream) {
    const float* x = (const float*)d_in[0];
    const float* cb = (const float*)d_in[1];
    float* out = (float*)d_out;

    if (ws_size >= WS_NEEDED) {
        unsigned char* ws = (unsigned char*)d_ws;
        unsigned short* xbf = (unsigned short*)(ws + O_XBF);
        uint4* qperm = (uint4*)(ws + O_QPERM);
        float* x2 = (float*)(ws + O_X2);
        float* e2 = (float*)(ws + O_E2);
        int* e2max_bits = (int*)(ws + O_E2MAX);

        void* args[] = {(void*)&x, (void*)&cb, (void*)&qperm, (void*)&e2,
                        (void*)&e2max_bits, (void*)&out};
        hipError_t err = hipLaunchCooperativeKernel((const void*)vq_fused_kernel,
                                                    dim3(N_ROWS / 64), dim3(512),
                                                    args, 0, stream);
        if (err != hipSuccess) {
            // fallback: verified round-8 two-kernel path
            prep_kernel<<<(N_ROWS + KCODES) / 64, 256, 0, stream>>>(x, cb, xbf, qperm, x2,
                                                                    e2, e2max_bits);
            screen_fused_kernel<<<N_ROWS / 64, 512, 0, stream>>>(xbf, qperm, x, cb, x2, e2,
                                                                 e2max_bits, out);
        }
    } else {
        float* ws = (float*)d_ws;
        float* e2 = ws;
        float* x2 = ws + KCODES;
        float2* partial = (float2*)(ws + KCODES + N_ROWS);
        sumsq_kernel<<<(KCODES + N_ROWS) / 256, 256, 0, stream>>>(x, cb, ws);
        dim3 grid(N_ROWS / TM, SPLITK);
        dist_argmin_kernel<<<grid, 256, 0, stream>>>(x, cb, e2, x2, partial);
        finalize_kernel<<<(N_ROWS * 4) / 256, 256, 0, stream>>>(partial, x, cb, out);
    }
}

// Round 10
// 138.164 us; speedup vs baseline: 1.8427x; 1.8427x over previous
//
#include <hip/hip_runtime.h>
#include <hip/hip_bf16.h>
#include <math.h>

// Problem constants (B=16, T=2048, D=64, K=8192)
#define N_ROWS 32768
#define KCODES 8192
#define DDIM 64

typedef __attribute__((ext_vector_type(8))) short bf16x8;
typedef __attribute__((ext_vector_type(4))) float f32x4;

// ===================== FAST PATH =====================
// ws layout (bytes):
//   O_XBF   = 0        : (fallback path scratch)
//   O_QPERM = 4 MB     : codebook in MFMA-B-frag order (1 MB)
//   O_X2    = 5242880  : (fallback path)
//   O_E2    = 5373952  : e2  K f32
//   O_E2MAX = 5406720  : 1 f32 (atomicMax int-bits)
#define O_XBF   0
#define O_QPERM 4194304UL
#define O_X2    5242880UL
#define O_E2    5373952UL
#define O_E2MAX 5406720UL
#define O_SLOTS 5668880UL
#define WS_NEEDED (O_SLOTS + (size_t)N_ROWS * 16 * 4)
#define CAPL 32  // LDS candidate capacity per row (observed ~1-2; overflow has exact fallback)

__device__ __forceinline__ unsigned short f2bf(float f) {
    __hip_bfloat16 h = __float2bfloat16(f);  // RNE
    union { __hip_bfloat16 b; unsigned short u; } u;
    u.b = h;
    return u.u;
}

__device__ __forceinline__ float bf2f(unsigned short u) {
    return __uint_as_float(((unsigned int)u) << 16);  // exact bf16 -> f32
}

// prep (codebook only): cb -> qperm (frag order) + e2 + e2max. 4 thr/row, LDS-staged
// exact v1 sumsq (same 8-accumulator order, contract off) -> e2/e2max bit-equal to the
// validated values. Grid KCODES/64 = 128 blocks x 256 thr.
__global__ __launch_bounds__(256) void prep_cb_kernel(const float* __restrict__ cb,
                                                      uint4* __restrict__ qperm,
                                                      float* __restrict__ e2,
                                                      int* __restrict__ e2max_bits) {
#pragma clang fp contract(off)
    __shared__ float xrow[64][68];  // 64 rows x 64 f32, pad to 68

    const int tid = threadIdx.x;
    const int rloc = tid >> 2;  // row within block
    const int q4 = tid & 3;     // quarter within row
    const int r = blockIdx.x * 64 + rloc;  // code row 0..8191
    const float* src = cb + (size_t)r * DDIM;

    float4 v[4];
#pragma unroll
    for (int h2 = 0; h2 < 4; ++h2) v[h2] = ((const float4*)src)[q4 * 4 + h2];
#pragma unroll
    for (int h2 = 0; h2 < 4; ++h2)
        *(float4*)&xrow[rloc][q4 * 16 + h2 * 4] = v[h2];

    uint4 ch[2];
#pragma unroll
    for (int hh = 0; hh < 2; ++hh) {
        float4 v0 = v[hh * 2];
        float4 v1 = v[hh * 2 + 1];
        ushort4 a, b;
        a.x = f2bf(v0.x); a.y = f2bf(v0.y); a.z = f2bf(v0.z); a.w = f2bf(v0.w);
        b.x = f2bf(v1.x); b.y = f2bf(v1.y); b.z = f2bf(v1.z); b.w = f2bf(v1.w);
        union { struct { ushort4 lo, hi; } s; uint4 u; } pk;
        pk.s.lo = a; pk.s.hi = b;
        ch[hh] = pk.u;
    }
    {
        // frag-order: slot = ((r>>4)*2 + (h>>2))*64 + (h&3)*16 + (r&15)
        const int g = r >> 4, l15 = r & 15;
#pragma unroll
        for (int hh = 0; hh < 2; ++hh) {
            const int h = q4 * 2 + hh;
            const int slot = (g * 2 + (h >> 2)) * 64 + (h & 3) * 16 + l15;
            qperm[slot] = ch[hh];
        }
    }
    __syncthreads();

    // exact numpy-pairwise sumsq, one thread per row (identical op sequence to v1)
    if (tid < 64) {
        float acc[8];
#pragma unroll
        for (int j = 0; j < 8; ++j) { float vv = xrow[tid][j]; acc[j] = vv * vv; }
#pragma unroll
        for (int i = 8; i < 64; i += 8)
#pragma unroll
            for (int j = 0; j < 8; ++j) { float vv = xrow[tid][i + j]; acc[j] = acc[j] + vv * vv; }
        float s = ((acc[0] + acc[1]) + (acc[2] + acc[3])) + ((acc[4] + acc[5]) + (acc[6] + acc[7]));
        e2[blockIdx.x * 64 + tid] = s;
        float wm = s;
#pragma unroll
        for (int m = 1; m < 64; m <<= 1) wm = fmaxf(wm, __shfl_xor(wm, m, 64));
        if (tid == 0) atomicMax(e2max_bits, __float_as_int(wm));
    }
}

// ---- fused screen+finalize v3: one block = 64 rows x ALL 8192 codes, 8 waves.
// Phase 0a (verified round 9, absmax 0): block converts its own 64 x-rows -> xs_lds
//   (bf16) + x2_lds (exact v1 sumsq via 8-lane shfl; contract off). Block-local,
//   no grid sync needed. Eliminates the global xbf round-trip.
// Phase A (round-6/8-verified): 2-deep-prefetch MFMA sweep on s = dot - e2/2 (e2
//   folded into MFMA C-init), per-row per-128-code-group maxima -> LDS; s_setprio(1)
//   around the MFMA cluster (waves are barrier-free/independent here - T5 regime).
// Threshold: per-row gmax from tilemax, thr = gmax - margin (validated s-space margin).
// Phase B (row-exact): worklist of (row,group) pairs with tilemax >= thr[row]; fp32
//   fmaf re-score of the SAME bf16 inputs; candidates -> LDS lists.
// Phase C (== old finalize2 arithmetic, validated absmax 0): exact fp32 re-score,
//   8 lanes/row, lexicographic (dist,code) min; writes x_q_st and index.
__global__ __launch_bounds__(512) void screen_fused_kernel(
    const float* __restrict__ xg, const float* __restrict__ cbg,
    const uint4* __restrict__ qperm, const float* __restrict__ e2g,
    const int* __restrict__ e2max_bits, float* __restrict__ out) {
#pragma clang fp contract(off)
    __shared__ float tilemax_lds[64 * 64];       // [group g=0..63][row r=0..63], 16 KB
    __shared__ unsigned short xs_lds[64][64];    // bf16 x rows, 8 KB
    __shared__ unsigned int wl[4096];            // worklist (g<<6)|r, 16 KB
    __shared__ float thr_lds[64];                // per-row threshold in s-space
    __shared__ float x2_lds[64];                 // per-row x2 (exact v1 value)
    __shared__ int cnt_lds[64];                  // per-row candidate counts
    __shared__ int slots_lds[64][CAPL];          // per-row candidate codes, 8 KB
    __shared__ int wcnt;

    const int tid = threadIdx.x;
    const int w = tid >> 6;      // wave 0..7
    const int lane = tid & 63;
    const int l15 = lane & 15;
    const int quad = lane >> 4;
    const int row0 = blockIdx.x * 64;
    const int T0 = w * 64;       // this wave's first 16-code tile (of 512 total)

    if (tid == 0) wcnt = 0;
    if (tid < 64) cnt_lds[tid] = 0;

    // ---------------- Phase 0a: own 64 x-rows -> xs_lds + x2_lds ----------------
    {
        const int r0 = tid >> 3;  // row 0..63
        const int h0 = tid & 7;   // 8-float chunk 0..7
        const float* src = xg + (size_t)(row0 + r0) * DDIM + h0 * 8;
        float4 v0 = ((const float4*)src)[0];
        float4 v1 = ((const float4*)src)[1];
        ushort4 a, b;
        a.x = f2bf(v0.x); a.y = f2bf(v0.y); a.z = f2bf(v0.z); a.w = f2bf(v0.w);
        b.x = f2bf(v1.x); b.y = f2bf(v1.y); b.z = f2bf(v1.z); b.w = f2bf(v1.w);
        union { struct { ushort4 lo, hi; } s; uint4 u; } pk;
        pk.s.lo = a; pk.s.hi = b;
        *(uint4*)&xs_lds[r0][h0 * 8] = pk.u;

        // exact v1 sumsq: sq per lane (contract off), sequential m=0..7 adds per j,
        // then v1's pairwise tree. Lane base+m holds chunk m of the row.
        float sq[8] = {v0.x * v0.x, v0.y * v0.y, v0.z * v0.z, v0.w * v0.w,
                       v1.x * v1.x, v1.y * v1.y, v1.z * v1.z, v1.w * v1.w};
        const int base = lane & ~7;
        float acc[8];
#pragma unroll
        for (int j = 0; j < 8; ++j) acc[j] = __shfl(sq[j], base, 64);
#pragma unroll
        for (int m = 1; m < 8; ++m)
#pragma unroll
            for (int j = 0; j < 8; ++j) acc[j] = acc[j] + __shfl(sq[j], base + m, 64);
        float s = ((acc[0] + acc[1]) + (acc[2] + acc[3])) +
                  ((acc[4] + acc[5]) + (acc[6] + acc[7]));
        if (h0 == 0) x2_lds[r0] = s;
    }
    __syncthreads();  // xs_lds ready for afrag loads

    // A-fragments from LDS (same values/layout as prior global xbf reads; f2bf is
    // deterministic RNE so bits match the old path exactly)
    bf16x8 afrag[4][2];
#pragma unroll
    for (int rt = 0; rt < 4; ++rt)
#pragma unroll
        for (int s = 0; s < 2; ++s)
            afrag[rt][s] = *(const bf16x8*)&xs_lds[rt * 16 + l15][s * 32 + quad * 8];

    const uint4* pB = qperm + (size_t)T0 * 128 + lane;
    const float* pE = e2g + T0 * 16 + l15;

    // ---------------- Phase A: full sweep with tilemax tracking ----------------
    bf16x8 b0[2], b1[2];
    float ee2[2];
#pragma unroll
    for (int i = 0; i < 2; ++i) {
        b0[i] = *(const bf16x8*)(pB + (size_t)i * 128);
        b1[i] = *(const bf16x8*)(pB + (size_t)i * 128 + 64);
        ee2[i] = pE[i * 16];
    }

    float tmax[4][4];
#pragma unroll
    for (int rt = 0; rt < 4; ++rt)
#pragma unroll
        for (int reg = 0; reg < 4; ++reg) tmax[rt][reg] = -3.0e38f;

    for (int g = 0; g < 8; ++g) {
#pragma unroll 2
        for (int j = 0; j < 8; ++j) {
            const int t = g * 8 + j;
            const int buf = t & 1;
            const bf16x8 B0 = b0[buf];
            const bf16x8 B1 = b1[buf];
            const float eh = -0.5f * ee2[buf];
            if (t < 62) {
                const uint4* p = pB + (size_t)(t + 2) * 128;
                b0[buf] = *(const bf16x8*)p;
                b1[buf] = *(const bf16x8*)(p + 64);
                ee2[buf] = pE[(t + 2) * 16];
            }
            const f32x4 cin = {eh, eh, eh, eh};
            __builtin_amdgcn_s_setprio(1);
#pragma unroll
            for (int rt = 0; rt < 4; ++rt) {
                f32x4 acc = __builtin_amdgcn_mfma_f32_16x16x32_bf16(afrag[rt][0], B0, cin, 0, 0, 0);
                acc = __builtin_amdgcn_mfma_f32_16x16x32_bf16(afrag[rt][1], B1, acc, 0, 0, 0);
#pragma unroll
                for (int reg = 0; reg < 4; ++reg)
                    tmax[rt][reg] = fmaxf(tmax[rt][reg], acc[reg]);
            }
            __builtin_amdgcn_s_setprio(0);
        }
        // group-end: reduce over the 16 code-columns (l15 lanes), commit per-row tile max
        const int gidx = w * 8 + g;
#pragma unroll
        for (int rt = 0; rt < 4; ++rt)
#pragma unroll
            for (int reg = 0; reg < 4; ++reg) {
                float v = tmax[rt][reg];
                v = fmaxf(v, __shfl_xor(v, 1, 64));
                v = fmaxf(v, __shfl_xor(v, 2, 64));
                v = fmaxf(v, __shfl_xor(v, 4, 64));
                v = fmaxf(v, __shfl_xor(v, 8, 64));
                if (l15 == 0) tilemax_lds[gidx * 64 + rt * 16 + quad * 4 + reg] = v;
                tmax[rt][reg] = -3.0e38f;
            }
    }
    __syncthreads();

    // ---------------- block-local gmax -> threshold ----------------
    if (tid < 64) {
        float gs = -3.0e38f;
        for (int e = 0; e < 64; ++e) gs = fmaxf(gs, tilemax_lds[e * 64 + tid]);
        const float e2max = __int_as_float(*e2max_bits);
        // s-space margin == half the validated dist-space margin (dist = x2 - 2s)
        thr_lds[tid] = gs - 0.005f * sqrtf(x2_lds[tid] * e2max) - 0.01f;
    }
    __syncthreads();

    // ---------------- worklist build: row-exact (row, group) pairs ----------------
    for (int idx = tid; idx < 4096; idx += 512) {
        if (tilemax_lds[idx] >= thr_lds[idx & 63]) {
            int pos = atomicAdd(&wcnt, 1);
            wl[pos] = (unsigned int)idx;  // layout [g][r]: idx = (g<<6)|r
        }
    }
    __syncthreads();

    // ---------------- Phase B: VALU re-score of flagged pairs only ----------------
    const int nwl = wcnt;
    for (int p = w; p < nwl; p += 8) {
        const unsigned int e = wl[p];
        const int r = (int)(e & 63u);
        const int g = (int)(e >> 6);
        const float thr_r = thr_lds[r];
#pragma unroll
        for (int hh = 0; hh < 2; ++hh) {
            const int c = g * 128 + hh * 64 + lane;
            float s = -0.5f * e2g[c];
            const int cg = c >> 4, cl = c & 15;
#pragma unroll
            for (int h = 0; h < 8; ++h) {
                const int slot = (cg * 2 + (h >> 2)) * 64 + (h & 3) * 16 + cl;
                union { uint4 u; unsigned short us[8]; } qd, xd;
                qd.u = qperm[slot];
                xd.u = *(const uint4*)&xs_lds[r][h * 8];
#pragma unroll
                for (int k = 0; k < 8; ++k)
                    s = fmaf(bf2f(xd.us[k]), bf2f(qd.us[k]), s);
            }
            if (s >= thr_r) {  // ~1-2 codes/row over all K
                int pos = atomicAdd(&cnt_lds[r], 1);
                if (pos < CAPL) slots_lds[r][pos] = c;
            }
        }
    }
    __syncthreads();

    // ---------------- Phase C: exact fp32 re-score + output (== old finalize2) -------
    const int sub = lane >> 3;   // row within wave's 8-row group
    const int ln8 = lane & 7;    // 8 lanes per row
    const int r = w * 8 + sub;
    const int row = row0 + r;
    const int c = cnt_lds[r];
    const float x2v = x2_lds[r];
    const float4* xv4 = (const float4*)(xg + (size_t)row * DDIM);

    float bv = 3.0e38f;
    int bi = 0x7fffffff;
    if (c <= CAPL) {
        for (int i = ln8; i < c; i += 8) {
            int code = slots_lds[r][i];
            float xe = 0.0f;
            const float4* e4 = (const float4*)(cbg + (size_t)code * DDIM);
#pragma unroll
            for (int q = 0; q < 16; ++q) {
                float4 xv = xv4[q];
                float4 ev = e4[q];
                xe = fmaf(xv.x, ev.x, xe);
                xe = fmaf(xv.y, ev.y, xe);
                xe = fmaf(xv.z, ev.z, xe);
                xe = fmaf(xv.w, ev.w, xe);
            }
            float ts = x2v + e2g[code];
            float dist = fmaf(-2.0f, xe, ts);
            if (dist < bv || (dist == bv && code < bi)) { bv = dist; bi = code; }
        }
    } else {
        // backstop: full scan (overflow; should never trigger)
        for (int code = ln8; code < KCODES; code += 8) {
            float xe = 0.0f;
            const float4* e4 = (const float4*)(cbg + (size_t)code * DDIM);
#pragma unroll
            for (int q = 0; q < 16; ++q) {
                float4 xv = xv4[q];
                float4 ev = e4[q];
                xe = fmaf(xv.x, ev.x, xe);
                xe = fmaf(xv.y, ev.y, xe);
                xe = fmaf(xv.z, ev.z, xe);
                xe = fmaf(xv.w, ev.w, xe);
            }
            float ts = x2v + e2g[code];
            float dist = fmaf(-2.0f, xe, ts);
            if (dist < bv || (dist == bv && code < bi)) { bv = dist; bi = code; }
        }
    }
    // 8-lane lexicographic (dist, code) min reduce (associative + commutative)
#pragma unroll
    for (int m = 1; m < 8; m <<= 1) {
        float ov = __shfl_xor(bv, m, 64);
        int oi = __shfl_xor(bi, m, 64);
        if (ov < bv || (ov == bv && oi < bi)) { bv = ov; bi = oi; }
    }
    // outputs: x_q_st = x + (q - x), elementwise f32 (identical to old finalize2)
    {
        const float4* qs4 = (const float4*)(cbg + (size_t)bi * DDIM);
        float4* os4 = (float4*)(out + (size_t)row * DDIM);
#pragma unroll
        for (int i = 0; i < 2; ++i) {
            float4 xv = xv4[ln8 * 2 + i];
            float4 qv = qs4[ln8 * 2 + i];
            float4 ov;
            ov.x = xv.x + (qv.x - xv.x);
            ov.y = xv.y + (qv.y - xv.y);
            ov.z = xv.z + (qv.z - xv.z);
            ov.w = xv.w + (qv.w - xv.w);
            os4[ln8 * 2 + i] = ov;
        }
        if (ln8 == 0) out[(size_t)N_ROWS * DDIM + row] = (float)bi;
    }
}

// ===================== FALLBACK PATH (round-1, correct at 493 us) =====================
#define SPLITK 4
#define KPER (KCODES / SPLITK)
#define TM 128
#define TKT 128
#define NTILES (KPER / TKT)
#define LDSX 132
#define LDSE 132

__global__ __launch_bounds__(256) void sumsq_kernel(const float* __restrict__ x,
                                                    const float* __restrict__ cb,
                                                    float* __restrict__ ws) {
#pragma clang fp contract(off)
    int t = blockIdx.x * 256 + threadIdx.x;
    const float* src;
    float* dst;
    if (t < KCODES) { src = cb + (size_t)t * DDIM; dst = ws + t; }
    else { int r = t - KCODES; src = x + (size_t)r * DDIM; dst = ws + KCODES + r; }
    float acc[8];
#pragma unroll
    for (int j = 0; j < 8; ++j) { float v = src[j]; acc[j] = v * v; }
#pragma unroll
    for (int i = 8; i < 64; i += 8)
#pragma unroll
        for (int j = 0; j < 8; ++j) { float v = src[i + j]; acc[j] = acc[j] + v * v; }
    *dst = ((acc[0] + acc[1]) + (acc[2] + acc[3])) + ((acc[4] + acc[5]) + (acc[6] + acc[7]));
}

__global__ __launch_bounds__(256) void dist_argmin_kernel(const float* __restrict__ x,
                                                          const float* __restrict__ cb,
                                                          const float* __restrict__ e2g,
                                                          const float* __restrict__ x2g,
                                                          float2* __restrict__ partial) {
    __shared__ float smem[DDIM * LDSX + DDIM * LDSE];
    float* Xs = smem;
    float* Es = smem + DDIM * LDSX;
    const int tid = threadIdx.x;
    const int row0 = blockIdx.x * TM;
    const int code0 = blockIdx.y * KPER;
    const int tr = tid >> 4, tc = tid & 15;
    for (int i = tid; i < TM * 16; i += 256) {
        int r = i >> 4, q = i & 15;
        float4 v = ((const float4*)(x + (size_t)(row0 + r) * DDIM))[q];
        Xs[(4 * q + 0) * LDSX + r] = v.x; Xs[(4 * q + 1) * LDSX + r] = v.y;
        Xs[(4 * q + 2) * LDSX + r] = v.z; Xs[(4 * q + 3) * LDSX + r] = v.w;
    }
    float x2v[8];
#pragma unroll
    for (int j = 0; j < 8; ++j) x2v[j] = x2g[row0 + tr * 8 + j];
    float bestV[8]; int bestI[8];
#pragma unroll
    for (int j = 0; j < 8; ++j) { bestV[j] = 3.0e38f; bestI[j] = 0; }
    for (int t = 0; t < NTILES; ++t) {
        __syncthreads();
        const int cbase = code0 + t * TKT;
        for (int i = tid; i < TKT * 16; i += 256) {
            int c = i >> 4, q = i & 15;
            float4 v = ((const float4*)(cb + (size_t)(cbase + c) * DDIM))[q];
            Es[(4 * q + 0) * LDSE + c] = v.x; Es[(4 * q + 1) * LDSE + c] = v.y;
            Es[(4 * q + 2) * LDSE + c] = v.z; Es[(4 * q + 3) * LDSE + c] = v.w;
        }
        __syncthreads();
        float acc[8][8];
#pragma unroll
        for (int a = 0; a < 8; ++a)
#pragma unroll
            for (int b = 0; b < 8; ++b) acc[a][b] = 0.0f;
#pragma unroll 4
        for (int d = 0; d < DDIM; ++d) {
            float xv[8], ev[8];
            float4 xa = *(const float4*)&Xs[d * LDSX + tr * 8];
            float4 xb = *(const float4*)&Xs[d * LDSX + tr * 8 + 4];
            float4 ea = *(const float4*)&Es[d * LDSE + tc * 8];
            float4 eb = *(const float4*)&Es[d * LDSE + tc * 8 + 4];
            xv[0] = xa.x; xv[1] = xa.y; xv[2] = xa.z; xv[3] = xa.w;
            xv[4] = xb.x; xv[5] = xb.y; xv[6] = xb.z; xv[7] = xb.w;
            ev[0] = ea.x; ev[1] = ea.y; ev[2] = ea.z; ev[3] = ea.w;
            ev[4] = eb.x; ev[5] = eb.y; ev[6] = eb.z; ev[7] = eb.w;
#pragma unroll
            for (int a = 0; a < 8; ++a)
#pragma unroll
                for (int b = 0; b < 8; ++b) acc[a][b] = fmaf(xv[a], ev[b], acc[a][b]);
        }
#pragma unroll
        for (int b = 0; b < 8; ++b) {
            int ci = cbase + tc * 8 + b;
            float e2 = e2g[ci];
#pragma unroll
            for (int a = 0; a < 8; ++a) {
                float ts = x2v[a] + e2;
                float dist = fmaf(-2.0f, acc[a][b], ts);
                if (dist < bestV[a]) { bestV[a] = dist; bestI[a] = ci; }
            }
        }
    }
    __syncthreads();
    float* redV = Es;
    int* redI = (int*)(Es + TM * 16);
#pragma unroll
    for (int a = 0; a < 8; ++a) {
        redV[(tr * 8 + a) * 16 + tc] = bestV[a];
        redI[(tr * 8 + a) * 16 + tc] = bestI[a];
    }
    __syncthreads();
    if (tid < TM) {
        float bv = redV[tid * 16];
        int bi = redI[tid * 16];
#pragma unroll
        for (int c = 1; c < 16; ++c) {
            float v = redV[tid * 16 + c];
            int ii = redI[tid * 16 + c];
            if (v < bv || (v == bv && ii < bi)) { bv = v; bi = ii; }
        }
        partial[(size_t)(row0 + tid) * SPLITK + blockIdx.y] = make_float2(bv, __int_as_float(bi));
    }
}

__global__ __launch_bounds__(256) void finalize_kernel(const float2* __restrict__ partial,
                                                       const float* __restrict__ x,
                                                       const float* __restrict__ cb,
                                                       float* __restrict__ out) {
    int t = blockIdx.x * 256 + threadIdx.x;
    int r = t >> 2, j = t & 3;
    float2 p = partial[(size_t)r * SPLITK];
    float bv = p.x;
    int bi = __float_as_int(p.y);
#pragma unroll
    for (int k = 1; k < SPLITK; ++k) {
        float2 q = partial[(size_t)r * SPLITK + k];
        int qi = __float_as_int(q.y);
        if (q.x < bv || (q.x == bv && qi < bi)) { bv = q.x; bi = qi; }
    }
    const float4* xs = (const float4*)(x + (size_t)r * DDIM);
    const float4* qs = (const float4*)(cb + (size_t)bi * DDIM);
    float4* os = (float4*)(out + (size_t)r * DDIM);
#pragma unroll
    for (int i = 0; i < 4; ++i) {
        float4 xv = xs[j * 4 + i];
        float4 qv = qs[j * 4 + i];
        float4 ov;
        ov.x = xv.x + (qv.x - xv.x); ov.y = xv.y + (qv.y - xv.y);
        ov.z = xv.z + (qv.z - xv.z); ov.w = xv.w + (qv.w - xv.w);
        os[j * 4 + i] = ov;
    }
    if (j == 0) out[(size_t)N_ROWS * DDIM + r] = (float)bi;
}

// ===================== LAUNCH =====================
extern "C" void kernel_launch(void* const* d_in, const int* in_sizes, int n_in,
                              void* d_out, int out_size, void* d_ws, size_t ws_size,
                              hipStream_t stream) {
    const float* x = (const float*)d_in[0];
    const float* cb = (const float*)d_in[1];
    float* out = (float*)d_out;

    if (ws_size >= WS_NEEDED) {
        unsigned char* ws = (unsigned char*)d_ws;
        uint4* qperm = (uint4*)(ws + O_QPERM);
        float* e2 = (float*)(ws + O_E2);
        int* e2max_bits = (int*)(ws + O_E2MAX);

        prep_cb_kernel<<<KCODES / 64, 256, 0, stream>>>(cb, qperm, e2, e2max_bits);
        screen_fused_kernel<<<N_ROWS / 64, 512, 0, stream>>>(x, cb, qperm, e2,
                                                             e2max_bits, out);
    } else {
        float* ws = (float*)d_ws;
        float* e2 = ws;
        float* x2 = ws + KCODES;
        float2* partial = (float2*)(ws + KCODES + N_ROWS);
        sumsq_kernel<<<(KCODES + N_ROWS) / 256, 256, 0, stream>>>(x, cb, ws);
        dim3 grid(N_ROWS / TM, SPLITK);
        dist_argmin_kernel<<<grid, 256, 0, stream>>>(x, cb, e2, x2, partial);
        finalize_kernel<<<(N_ROWS * 4) / 256, 256, 0, stream>>>(partial, x, cb, out);
    }
}